// Round 1
// baseline (126.142 us; speedup 1.0000x reference)
//
#include <hip/hip_runtime.h>

// ExplicitLiePE: y[b,s] = expm(A) @ x[b,s],  A = sum_k r[b,s,k] * 0.5*(L_k - L_k^T)
// (P_sp = identity in this config).
//
// TWO tokens per wave: lane i holds row i of 2*A/rho for token A (rowA[64]) and
// token B (rowB[64]). The two Clenshaw/Miller chains are interleaved in the same
// unrolled loop so every readlane/fmac of one token fills dependency-stall slots
// of the other (the prior 1-token version measured VALUBusy ~50% at 2 waves/SIMD:
// issue-starved, not FLOP-bound).
//
// Unified loop runs m = max(M_A,M_B)+10 .. 1 with per-token predication:
//  - Miller backward recurrence seeded when m == ms_t (jc=1e-12, jp=0) — before
//    its seed a token's state is exactly 0, so the shared recurrence is a no-op.
//  - Chebyshev coefficient a_m = 2*J~_m gated by (m <= M_t); for m>M_t the
//    token's b1=b2=0 and a_m=0, so b stays exactly 0 until its own degree —
//    per-token arithmetic is identical to the single-token version.

#define TPB 256
#define TOKENS_PER_BLOCK 8       // 4 waves x 2 tokens per wave
#define LPAD 66                  // row stride (floats): float2-aligned rows; both
                                 // row (2*lane+j banks) and col (consecutive-lane)
                                 // LDS reads are <=2-way (free)
#define LSTRIDE (64 * LPAD)

__device__ __forceinline__ float bcast(float v, int l) {
    return __int_as_float(__builtin_amdgcn_readlane(__float_as_int(v), l));
}

__global__ __launch_bounds__(TPB, 2) void liepe_kernel(
    const float* __restrict__ x,
    const float* __restrict__ r_grid,
    const float* __restrict__ L_param,
    float* __restrict__ out,
    int n_tokens)
{
    __shared__ __align__(16) float Lsh[3 * LSTRIDE];

    // Stage raw L (3x64x64) into LDS, padded stride. Coalesced global reads.
    for (int idx = threadIdx.x; idx < 3 * 64 * 64; idx += TPB) {
        int k = idx >> 12;
        int rem = idx & 4095;
        int i = rem >> 6;
        int j = rem & 63;
        Lsh[k * LSTRIDE + i * LPAD + j] = L_param[idx];
    }
    __syncthreads();

    const int lane = threadIdx.x & 63;
    const int wid  = threadIdx.x >> 6;
    const int bsA  = blockIdx.x * TOKENS_PER_BLOCK + wid * 2;
    if (bsA >= n_tokens) return;
    int bsB = bsA + 1;
    const bool hasB = (bsB < n_tokens);
    if (!hasB) bsB = bsA;

    const float rA0 = r_grid[bsA * 3 + 0];
    const float rA1 = r_grid[bsA * 3 + 1];
    const float rA2 = r_grid[bsA * 3 + 2];
    const float rB0 = r_grid[bsB * 3 + 0];
    const float rB1 = r_grid[bsB * 3 + 1];
    const float rB2 = r_grid[bsB * 3 + 2];

    const float sigA = 0.5f * (rA0 * rA0 + rA1 * rA1 + rA2 * rA2);
    const float sigB = 0.5f * (rB0 * rB0 + rB1 * rB1 + rB2 * rB2);
    const float rhoA = fmaf(17.3f, __builtin_sqrtf(sigA), 2.0f);
    const float rhoB = fmaf(17.3f, __builtin_sqrtf(sigB), 2.0f);
    const float invA = 1.0f / rhoA;
    const float invB = 1.0f / rhoB;
    const int   MA   = (int)rhoA + 14;   // >= ceil(rho)+13 -> tail ~1e-4
    const int   MB   = (int)rhoB + 14;
    const int   msA  = MA + 10;
    const int   msB  = MB + 10;

    const float cA0 = rA0 * invA, cA1 = rA1 * invA, cA2 = rA2 * invA;
    const float cB0 = rB0 * invB, cB1 = rB1 * invB, cB2 = rB2 * invB;

    // Build rows of 2A/rho for both tokens; the skew difference d = L[i][j]-L[j][i]
    // is token-independent -> LDS reads shared between A and B.
    float rowA[64], rowB[64];
    #pragma unroll
    for (int j2 = 0; j2 < 64; j2 += 2) {
        float aA0 = 0.f, aA1 = 0.f, aB0 = 0.f, aB1 = 0.f;
        #pragma unroll
        for (int k = 0; k < 3; ++k) {
            const float ckA = (k == 0) ? cA0 : ((k == 1) ? cA1 : cA2);
            const float ckB = (k == 0) ? cB0 : ((k == 1) ? cB1 : cB2);
            const float* base = &Lsh[k * LSTRIDE];
            float2 a = *(const float2*)(base + lane * LPAD + j2);   // row part
            float b0v = base[(j2 + 0) * LPAD + lane];               // col part
            float b1v = base[(j2 + 1) * LPAD + lane];
            float d0 = a.x - b0v;
            float d1 = a.y - b1v;
            aA0 = fmaf(ckA, d0, aA0);
            aA1 = fmaf(ckA, d1, aA1);
            aB0 = fmaf(ckB, d0, aB0);
            aB1 = fmaf(ckB, d1, aB1);
        }
        rowA[j2 + 0] = aA0; rowA[j2 + 1] = aA1;
        rowB[j2 + 0] = aB0; rowB[j2 + 1] = aB1;
    }

    const float xvA = x[bsA * 64 + lane];
    const float xvB = x[bsB * 64 + lane];

    const int maxM   = (MA > MB) ? MA : MB;
    const int mstart = maxM + 10;

    float jpA = 0.f, jcA = 0.f, NA = 0.f, b1A = 0.f, b2A = 0.f;
    float jpB = 0.f, jcB = 0.f, NB = 0.f, b1B = 0.f, b2B = 0.f;

    // ---- descent phase: Miller only, no matvec (all b's are exactly 0 here) ----
    #pragma unroll 1
    for (int m = mstart; m > maxM; --m) {
        if (m == msA) { jcA = 1e-12f; jpA = 0.f; NA = ((m & 1) == 0) ? 2e-12f : 0.f; }
        if (m == msB) { jcB = 1e-12f; jpB = 0.f; NB = ((m & 1) == 0) ? 2e-12f : 0.f; }
        const float twoM = 2.f * (float)m;
        float jmA = fmaf(twoM * invA, jcA, -jpA); jpA = jcA; jcA = jmA;
        float jmB = fmaf(twoM * invB, jcB, -jpB); jpB = jcB; jcB = jmB;
        const int mm = m - 1;
        if ((mm & 1) == 0) {
            NA += (mm > 0) ? (jmA + jmA) : jmA;
            NB += (mm > 0) ? (jmB + jmB) : jmB;
        }
    }

    // ---- main fused Miller+Clenshaw loop, both tokens interleaved ----
    #pragma unroll 1
    for (int m = maxM; m >= 1; --m) {
        if (m == msA) { jcA = 1e-12f; jpA = 0.f; NA = ((m & 1) == 0) ? 2e-12f : 0.f; }
        if (m == msB) { jcB = 1e-12f; jpB = 0.f; NB = ((m & 1) == 0) ? 2e-12f : 0.f; }

        float aA0 = 0.f, aA1 = 0.f, aA2 = 0.f, aA3 = 0.f;
        float aB0 = 0.f, aB1 = 0.f, aB2 = 0.f, aB3 = 0.f;
        #pragma unroll
        for (int j = 0; j < 64; j += 4) {
            float tA0 = bcast(b1A, j + 0);
            float tA1 = bcast(b1A, j + 1);
            float tA2 = bcast(b1A, j + 2);
            float tA3 = bcast(b1A, j + 3);
            float tB0 = bcast(b1B, j + 0);
            float tB1 = bcast(b1B, j + 1);
            float tB2 = bcast(b1B, j + 2);
            float tB3 = bcast(b1B, j + 3);
            aA0 = fmaf(rowA[j + 0], tA0, aA0);
            aA1 = fmaf(rowA[j + 1], tA1, aA1);
            aA2 = fmaf(rowA[j + 2], tA2, aA2);
            aA3 = fmaf(rowA[j + 3], tA3, aA3);
            aB0 = fmaf(rowB[j + 0], tB0, aB0);
            aB1 = fmaf(rowB[j + 1], tB1, aB1);
            aB2 = fmaf(rowB[j + 2], tB2, aB2);
            aB3 = fmaf(rowB[j + 3], tB3, aB3);
        }
        float tA = (aA0 + aA1) + (aA2 + aA3);          // (2A/rho) b1, token A
        float tB = (aB0 + aB1) + (aB2 + aB3);

        float cfA = (m <= MA) ? (jcA + jcA) : 0.f;     // coefficient gate
        float cfB = (m <= MB) ? (jcB + jcB) : 0.f;
        float bnA = fmaf(cfA, xvA, tA + b2A);
        float bnB = fmaf(cfB, xvB, tB + b2B);
        b2A = b1A; b1A = bnA;
        b2B = b1B; b1B = bnB;

        const float twoM = 2.f * (float)m;
        float jmA = fmaf(twoM * invA, jcA, -jpA); jpA = jcA; jcA = jmA;
        float jmB = fmaf(twoM * invB, jcB, -jpB); jpB = jcB; jcB = jmB;
        const int mm = m - 1;
        if ((mm & 1) == 0) {
            NA += (mm > 0) ? (jmA + jmA) : jmA;
            NB += (mm > 0) ? (jmB + jmB) : jmB;
        }
    }

    // jc = J~_0 (already folded into N). Final: b0 = J~_0 x + (2A/rho)b1 + b2;
    // result = (b0 - (A/rho) b1) / N  -- reuse t = (2A/rho) b1.
    {
        float aA0 = 0.f, aA1 = 0.f, aA2 = 0.f, aA3 = 0.f;
        float aB0 = 0.f, aB1 = 0.f, aB2 = 0.f, aB3 = 0.f;
        #pragma unroll
        for (int j = 0; j < 64; j += 4) {
            float tA0 = bcast(b1A, j + 0);
            float tA1 = bcast(b1A, j + 1);
            float tA2 = bcast(b1A, j + 2);
            float tA3 = bcast(b1A, j + 3);
            float tB0 = bcast(b1B, j + 0);
            float tB1 = bcast(b1B, j + 1);
            float tB2 = bcast(b1B, j + 2);
            float tB3 = bcast(b1B, j + 3);
            aA0 = fmaf(rowA[j + 0], tA0, aA0);
            aA1 = fmaf(rowA[j + 1], tA1, aA1);
            aA2 = fmaf(rowA[j + 2], tA2, aA2);
            aA3 = fmaf(rowA[j + 3], tA3, aA3);
            aB0 = fmaf(rowB[j + 0], tB0, aB0);
            aB1 = fmaf(rowB[j + 1], tB1, aB1);
            aB2 = fmaf(rowB[j + 2], tB2, aB2);
            aB3 = fmaf(rowB[j + 3], tB3, aB3);
        }
        float tA = (aA0 + aA1) + (aA2 + aA3);
        float tB = (aB0 + aB1) + (aB2 + aB3);
        float b0A = fmaf(jcA, xvA, tA + b2A);
        float b0B = fmaf(jcB, xvB, tB + b2B);
        float yA  = (b0A - 0.5f * tA) / NA;
        float yB  = (b0B - 0.5f * tB) / NB;
        out[bsA * 64 + lane] = yA;
        if (hasB) out[bsB * 64 + lane] = yB;
    }
}

extern "C" void kernel_launch(void* const* d_in, const int* in_sizes, int n_in,
                              void* d_out, int out_size, void* d_ws, size_t ws_size,
                              hipStream_t stream) {
    const float* x = (const float*)d_in[0];
    const float* r = (const float*)d_in[1];
    const float* L = (const float*)d_in[2];
    // d_in[3] = P_sp: identity (allow_mixing=False) -> R_eff = R_r.
    float* out = (float*)d_out;

    int n_tokens = in_sizes[0] / 64;  // B*S = 8192
    int grid = (n_tokens + TOKENS_PER_BLOCK - 1) / TOKENS_PER_BLOCK;
    liepe_kernel<<<grid, TPB, 0, stream>>>(x, r, L, out, n_tokens);
}

// Round 2
// 91.663 us; speedup vs baseline: 1.3761x; 1.3761x over previous
//
#include <hip/hip_runtime.h>

// ExplicitLiePE: y[b,s] = expm(A) @ x[b,s],  A = sum_k r[b,s,k] * 0.5*(L_k - L_k^T)
// (P_sp = identity in this config).
//
// TWO tokens per wave: lane i holds row i of 2*A/rho for token A (rowA[64]) and
// token B (rowB[64]). The two Clenshaw/Miller chains are interleaved so every
// readlane/fmac of one token fills dependency-stall slots of the other.
//
// Register control: round-1's __launch_bounds__(TPB,2) made the allocator target
// 4 waves/SIMD (VGPR=128) and spill both row arrays to scratch (330 MB/dispatch
// of HBM traffic). amdgpu_waves_per_eu(1,2) gives the allocator budget down to
// 1 wave (up to 512 VGPRs, demand ~170-270 -> no spill) and caps the occupancy
// target at 2 waves/SIMD so it never spills-for-occupancy.
//
// Unified loop runs m = max(M_A,M_B)+10 .. 1 with per-token predication:
//  - Miller backward recurrence seeded when m == ms_t (jc=1e-12, jp=0) — before
//    its seed a token's state is exactly 0, so the shared recurrence is a no-op.
//  - Chebyshev coefficient a_m = 2*J~_m gated by (m <= M_t); for m>M_t the
//    token's b1=b2=0 and a_m=0, so b stays exactly 0 until its own degree —
//    per-token arithmetic is identical to the single-token version.

#define TPB 256
#define TOKENS_PER_BLOCK 8       // 4 waves x 2 tokens per wave
#define LPAD 66                  // row stride (floats): float2-aligned rows; both
                                 // row (2*lane+j banks) and col (consecutive-lane)
                                 // LDS reads are <=2-way (free)
#define LSTRIDE (64 * LPAD)

__device__ __forceinline__ float bcast(float v, int l) {
    return __int_as_float(__builtin_amdgcn_readlane(__float_as_int(v), l));
}

__global__ __launch_bounds__(TPB)
__attribute__((amdgpu_waves_per_eu(1, 2)))
void liepe_kernel(
    const float* __restrict__ x,
    const float* __restrict__ r_grid,
    const float* __restrict__ L_param,
    float* __restrict__ out,
    int n_tokens)
{
    __shared__ __align__(16) float Lsh[3 * LSTRIDE];

    // Stage raw L (3x64x64) into LDS, padded stride. Coalesced global reads.
    for (int idx = threadIdx.x; idx < 3 * 64 * 64; idx += TPB) {
        int k = idx >> 12;
        int rem = idx & 4095;
        int i = rem >> 6;
        int j = rem & 63;
        Lsh[k * LSTRIDE + i * LPAD + j] = L_param[idx];
    }
    __syncthreads();

    const int lane = threadIdx.x & 63;
    const int wid  = threadIdx.x >> 6;
    const int bsA  = blockIdx.x * TOKENS_PER_BLOCK + wid * 2;
    if (bsA >= n_tokens) return;
    int bsB = bsA + 1;
    const bool hasB = (bsB < n_tokens);
    if (!hasB) bsB = bsA;

    const float rA0 = r_grid[bsA * 3 + 0];
    const float rA1 = r_grid[bsA * 3 + 1];
    const float rA2 = r_grid[bsA * 3 + 2];
    const float rB0 = r_grid[bsB * 3 + 0];
    const float rB1 = r_grid[bsB * 3 + 1];
    const float rB2 = r_grid[bsB * 3 + 2];

    const float sigA = 0.5f * (rA0 * rA0 + rA1 * rA1 + rA2 * rA2);
    const float sigB = 0.5f * (rB0 * rB0 + rB1 * rB1 + rB2 * rB2);
    const float rhoA = fmaf(17.3f, __builtin_sqrtf(sigA), 2.0f);
    const float rhoB = fmaf(17.3f, __builtin_sqrtf(sigB), 2.0f);
    const float invA = 1.0f / rhoA;
    const float invB = 1.0f / rhoB;
    const int   MA   = (int)rhoA + 14;   // >= ceil(rho)+13 -> tail ~1e-4
    const int   MB   = (int)rhoB + 14;
    const int   msA  = MA + 10;
    const int   msB  = MB + 10;

    const float cA0 = rA0 * invA, cA1 = rA1 * invA, cA2 = rA2 * invA;
    const float cB0 = rB0 * invB, cB1 = rB1 * invB, cB2 = rB2 * invB;

    // Build rows of 2A/rho for both tokens; the skew difference d = L[i][j]-L[j][i]
    // is token-independent -> LDS reads shared between A and B.
    float rowA[64], rowB[64];
    #pragma unroll
    for (int j2 = 0; j2 < 64; j2 += 2) {
        float aA0 = 0.f, aA1 = 0.f, aB0 = 0.f, aB1 = 0.f;
        #pragma unroll
        for (int k = 0; k < 3; ++k) {
            const float ckA = (k == 0) ? cA0 : ((k == 1) ? cA1 : cA2);
            const float ckB = (k == 0) ? cB0 : ((k == 1) ? cB1 : cB2);
            const float* base = &Lsh[k * LSTRIDE];
            float2 a = *(const float2*)(base + lane * LPAD + j2);   // row part
            float b0v = base[(j2 + 0) * LPAD + lane];               // col part
            float b1v = base[(j2 + 1) * LPAD + lane];
            float d0 = a.x - b0v;
            float d1 = a.y - b1v;
            aA0 = fmaf(ckA, d0, aA0);
            aA1 = fmaf(ckA, d1, aA1);
            aB0 = fmaf(ckB, d0, aB0);
            aB1 = fmaf(ckB, d1, aB1);
        }
        rowA[j2 + 0] = aA0; rowA[j2 + 1] = aA1;
        rowB[j2 + 0] = aB0; rowB[j2 + 1] = aB1;
    }

    const float xvA = x[bsA * 64 + lane];
    const float xvB = x[bsB * 64 + lane];

    const int maxM   = (MA > MB) ? MA : MB;
    const int mstart = maxM + 10;

    float jpA = 0.f, jcA = 0.f, NA = 0.f, b1A = 0.f, b2A = 0.f;
    float jpB = 0.f, jcB = 0.f, NB = 0.f, b1B = 0.f, b2B = 0.f;

    // ---- descent phase: Miller only, no matvec (all b's are exactly 0 here) ----
    #pragma unroll 1
    for (int m = mstart; m > maxM; --m) {
        if (m == msA) { jcA = 1e-12f; jpA = 0.f; NA = ((m & 1) == 0) ? 2e-12f : 0.f; }
        if (m == msB) { jcB = 1e-12f; jpB = 0.f; NB = ((m & 1) == 0) ? 2e-12f : 0.f; }
        const float twoM = 2.f * (float)m;
        float jmA = fmaf(twoM * invA, jcA, -jpA); jpA = jcA; jcA = jmA;
        float jmB = fmaf(twoM * invB, jcB, -jpB); jpB = jcB; jcB = jmB;
        const int mm = m - 1;
        if ((mm & 1) == 0) {
            NA += (mm > 0) ? (jmA + jmA) : jmA;
            NB += (mm > 0) ? (jmB + jmB) : jmB;
        }
    }

    // ---- main fused Miller+Clenshaw loop, both tokens interleaved ----
    #pragma unroll 1
    for (int m = maxM; m >= 1; --m) {
        if (m == msA) { jcA = 1e-12f; jpA = 0.f; NA = ((m & 1) == 0) ? 2e-12f : 0.f; }
        if (m == msB) { jcB = 1e-12f; jpB = 0.f; NB = ((m & 1) == 0) ? 2e-12f : 0.f; }

        float aA0 = 0.f, aA1 = 0.f, aA2 = 0.f, aA3 = 0.f;
        float aB0 = 0.f, aB1 = 0.f, aB2 = 0.f, aB3 = 0.f;
        #pragma unroll
        for (int j = 0; j < 64; j += 4) {
            float tA0 = bcast(b1A, j + 0);
            float tA1 = bcast(b1A, j + 1);
            float tA2 = bcast(b1A, j + 2);
            float tA3 = bcast(b1A, j + 3);
            float tB0 = bcast(b1B, j + 0);
            float tB1 = bcast(b1B, j + 1);
            float tB2 = bcast(b1B, j + 2);
            float tB3 = bcast(b1B, j + 3);
            aA0 = fmaf(rowA[j + 0], tA0, aA0);
            aA1 = fmaf(rowA[j + 1], tA1, aA1);
            aA2 = fmaf(rowA[j + 2], tA2, aA2);
            aA3 = fmaf(rowA[j + 3], tA3, aA3);
            aB0 = fmaf(rowB[j + 0], tB0, aB0);
            aB1 = fmaf(rowB[j + 1], tB1, aB1);
            aB2 = fmaf(rowB[j + 2], tB2, aB2);
            aB3 = fmaf(rowB[j + 3], tB3, aB3);
        }
        float tA = (aA0 + aA1) + (aA2 + aA3);          // (2A/rho) b1, token A
        float tB = (aB0 + aB1) + (aB2 + aB3);

        float cfA = (m <= MA) ? (jcA + jcA) : 0.f;     // coefficient gate
        float cfB = (m <= MB) ? (jcB + jcB) : 0.f;
        float bnA = fmaf(cfA, xvA, tA + b2A);
        float bnB = fmaf(cfB, xvB, tB + b2B);
        b2A = b1A; b1A = bnA;
        b2B = b1B; b1B = bnB;

        const float twoM = 2.f * (float)m;
        float jmA = fmaf(twoM * invA, jcA, -jpA); jpA = jcA; jcA = jmA;
        float jmB = fmaf(twoM * invB, jcB, -jpB); jpB = jcB; jcB = jmB;
        const int mm = m - 1;
        if ((mm & 1) == 0) {
            NA += (mm > 0) ? (jmA + jmA) : jmA;
            NB += (mm > 0) ? (jmB + jmB) : jmB;
        }
    }

    // jc = J~_0 (already folded into N). Final: b0 = J~_0 x + (2A/rho)b1 + b2;
    // result = (b0 - (A/rho) b1) / N  -- reuse t = (2A/rho) b1.
    {
        float aA0 = 0.f, aA1 = 0.f, aA2 = 0.f, aA3 = 0.f;
        float aB0 = 0.f, aB1 = 0.f, aB2 = 0.f, aB3 = 0.f;
        #pragma unroll
        for (int j = 0; j < 64; j += 4) {
            float tA0 = bcast(b1A, j + 0);
            float tA1 = bcast(b1A, j + 1);
            float tA2 = bcast(b1A, j + 2);
            float tA3 = bcast(b1A, j + 3);
            float tB0 = bcast(b1B, j + 0);
            float tB1 = bcast(b1B, j + 1);
            float tB2 = bcast(b1B, j + 2);
            float tB3 = bcast(b1B, j + 3);
            aA0 = fmaf(rowA[j + 0], tA0, aA0);
            aA1 = fmaf(rowA[j + 1], tA1, aA1);
            aA2 = fmaf(rowA[j + 2], tA2, aA2);
            aA3 = fmaf(rowA[j + 3], tA3, aA3);
            aB0 = fmaf(rowB[j + 0], tB0, aB0);
            aB1 = fmaf(rowB[j + 1], tB1, aB1);
            aB2 = fmaf(rowB[j + 2], tB2, aB2);
            aB3 = fmaf(rowB[j + 3], tB3, aB3);
        }
        float tA = (aA0 + aA1) + (aA2 + aA3);
        float tB = (aB0 + aB1) + (aB2 + aB3);
        float b0A = fmaf(jcA, xvA, tA + b2A);
        float b0B = fmaf(jcB, xvB, tB + b2B);
        float yA  = (b0A - 0.5f * tA) / NA;
        float yB  = (b0B - 0.5f * tB) / NB;
        out[bsA * 64 + lane] = yA;
        if (hasB) out[bsB * 64 + lane] = yB;
    }
}

extern "C" void kernel_launch(void* const* d_in, const int* in_sizes, int n_in,
                              void* d_out, int out_size, void* d_ws, size_t ws_size,
                              hipStream_t stream) {
    const float* x = (const float*)d_in[0];
    const float* r = (const float*)d_in[1];
    const float* L = (const float*)d_in[2];
    // d_in[3] = P_sp: identity (allow_mixing=False) -> R_eff = R_r.
    float* out = (float*)d_out;

    int n_tokens = in_sizes[0] / 64;  // B*S = 8192
    int grid = (n_tokens + TOKENS_PER_BLOCK - 1) / TOKENS_PER_BLOCK;
    liepe_kernel<<<grid, TPB, 0, stream>>>(x, r, L, out, n_tokens);
}